// Round 4
// baseline (164.750 us; speedup 1.0000x reference)
//
#include <hip/hip_runtime.h>
#include <math.h>
#include <float.h>

#define NB 4
#define NP 4096     // points (and vertices) per batch
#define NT 8192     // triangles
#define TSE 8       // floats per scan record  (2 x float4)
#define TEE 20      // floats per eval record  (5 x float4)
#define EPSD 1e-12
#define MNS 32      // main-pass splits
#define MTCH (NT/MNS)   // 256 triangles per split
#define NSEED 2048  // seed points = vertex 'a' of first 2048 triangles
#define VCH 8       // seed chunks
#define VLEN (NSEED/VCH)  // 256 seed points per chunk

__device__ __forceinline__ float sigm(float x) { return 1.0f / (1.0f + expf(-x)); }

// ---------------------------------------------------------------------------
// Exact point-triangle distance^2 — EXPRESSIONS IDENTICAL to the proven
// baseline kernel (bit-identical results on the evaluated set).
// ---------------------------------------------------------------------------
__device__ __forceinline__ float tri_dist(
    float px, float py, float pz,
    float ax, float ay, float az,
    float abx, float aby, float abz,
    float acx, float acy, float acz,
    float aa, float am, float cc,
    float raa, float rcc, float rbb,
    float rden, float den, float bb, float k1)
{
  float apx = px - ax, apy = py - ay, apz = pz - az;
  float d1   = apx*abx + apy*aby + apz*abz;
  float d2   = apx*acx + apy*acy + apz*acz;
  float apap = apx*apx + apy*apy + apz*apz;
  float vb = d1*cc - d2*am;
  float vc = d2*aa - d1*am;
  float va = den - vb - vc;
  float di = apap - (vb*d1 + vc*d2)*rden;          // interior (plane projection)
  float t2 = d1 + d1;
  float tab = fminf(fmaxf(d1*raa, 0.0f), 1.0f);
  float dAB = apap + tab*(tab*aa - t2);
  float t4 = d2 + d2;
  float tac = fminf(fmaxf(d2*rcc, 0.0f), 1.0f);
  float dAC = apap + tac*(tac*cc - t4);
  float e   = d2 - d1 + k1;
  float tbc = fminf(fmaxf(e*rbb, 0.0f), 1.0f);
  float distB = apap - t2 + aa;
  float dBC = distB + tbc*(tbc*bb - (e + e));
  float m3 = fminf(fminf(dAB, dAC), dBC);
  bool in = (vb >= 0.0f) & (vc >= 0.0f) & (va > 0.0f);
  return in ? di : m3;
}

// ---------------------------------------------------------------------------
// Kernel 1: per-(batch,triangle) precompute (sigmoid inlined — no pos array).
// triS (8 floats):  [nhx nhy nhz w | qx qy qz R]
//   nhat = (ab x ac)/sqrt(den*1.02) (2% slack baked in), w = -nhat.a
//     slab LB:   s = nhat.p + w;  prune-safe keep iff s^2 < mind + 1e-8
//   q = centroid, R = inflated circumradius around q:
//     sphere LB: keep iff |p-q|^2 < (smind + R)^2, smind = sqrt(mind)*1.005+1e-5
// triE (20 floats): [ax ay az abx | aby abz acx acy | acz aa am cc |
//                    raa rcc rbb rden | den bb k1 0]
// Also: t<NSEED writes vertex a to seedA (SoA); idx==0 zeroes the ticket.
// Degenerate (den~0): nhat=0,w=0 -> slab never prunes; sphere still valid.
// ---------------------------------------------------------------------------
__global__ __launch_bounds__(256) void prep_kernel(
    const float* __restrict__ verts, const int* __restrict__ faces,
    float* __restrict__ triS, float* __restrict__ triE,
    float* __restrict__ seedA, unsigned* __restrict__ cnt)
{
  int idx = blockIdx.x * 256 + threadIdx.x;
  if (idx == 0) *cnt = 0u;                 // ticket for fused reduce/final
  if (idx >= NB * NT) return;
  int b = idx >> 13;
  int t = idx & (NT - 1);
  int f0 = faces[3*t + 0], f1 = faces[3*t + 1], f2i = faces[3*t + 2];
  const float* vb_ = verts + (size_t)b * 3 * NP;
  float ax = sigm(vb_[f0]),  ay = sigm(vb_[NP + f0]),  az = sigm(vb_[2*NP + f0]);
  float bx = sigm(vb_[f1]),  by = sigm(vb_[NP + f1]),  bz = sigm(vb_[2*NP + f1]);
  float cx = sigm(vb_[f2i]), cy = sigm(vb_[NP + f2i]), cz = sigm(vb_[2*NP + f2i]);
  float abx = bx - ax, aby = by - ay, abz = bz - az;
  float acx = cx - ax, acy = cy - ay, acz = cz - az;
  double aa = (double)abx*abx + (double)aby*aby + (double)abz*abz;
  double am = (double)abx*acx + (double)aby*acy + (double)abz*acz;
  double cc = (double)acx*acx + (double)acy*acy + (double)acz*acz;
  double den = aa*cc - am*am;     // Gram determinant == |ab x ac|^2
  double bb  = aa - 2.0*am + cc;
  float raa  = (fabs(aa)  < EPSD) ? 1.0f : (float)(1.0/aa);
  float rcc  = (fabs(cc)  < EPSD) ? 1.0f : (float)(1.0/cc);
  float rbb  = (fabs(bb)  < EPSD) ? 1.0f : (float)(1.0/bb);
  float rden = (fabs(den) < EPSD) ? 0.0f : (float)(1.0/den);
  double nx = (double)aby*acz - (double)abz*acy;
  double ny = (double)abz*acx - (double)abx*acz;
  double nz = (double)abx*acy - (double)aby*acx;
  double rs = (fabs(den) < EPSD) ? 0.0 : 1.0 / sqrt(den * 1.02);
  float nhx = (float)(nx * rs), nhy = (float)(ny * rs), nhz = (float)(nz * rs);
  float w = (float)(-(nx*ax + ny*ay + nz*az) * rs);
  // centroid + inflated radius (covers all fp rounding in the sphere test)
  float qx = (ax + bx + cx) * (1.0f/3.0f);
  float qy = (ay + by + cy) * (1.0f/3.0f);
  float qz = (az + bz + cz) * (1.0f/3.0f);
  float r2a = (ax-qx)*(ax-qx) + (ay-qy)*(ay-qy) + (az-qz)*(az-qz);
  float r2b = (bx-qx)*(bx-qx) + (by-qy)*(by-qy) + (bz-qz)*(bz-qz);
  float r2c = (cx-qx)*(cx-qx) + (cy-qy)*(cy-qy) + (cz-qz)*(cz-qz);
  float R = sqrtf(fmaxf(r2a, fmaxf(r2b, r2c))) * 1.0005f + 1e-6f;
  float* rs_ = triS + (size_t)idx * TSE;
  rs_[0] = nhx; rs_[1] = nhy; rs_[2] = nhz; rs_[3] = w;
  rs_[4] = qx;  rs_[5] = qy;  rs_[6] = qz;  rs_[7] = R;
  float* re = triE + (size_t)idx * TEE;
  re[0]  = ax;  re[1]  = ay;  re[2]  = az;  re[3]  = abx;
  re[4]  = aby; re[5]  = abz; re[6]  = acx; re[7]  = acy;
  re[8]  = acz; re[9]  = (float)aa; re[10] = (float)am; re[11] = (float)cc;
  re[12] = raa; re[13] = rcc; re[14] = rbb; re[15] = rden;
  re[16] = (float)den; re[17] = (float)bb; re[18] = (float)(aa - am); re[19] = 0.0f;
  if (t < NSEED) {   // seed = vertex 'a' of first NSEED triangles: ON the mesh,
    float* sa = seedA + (size_t)b * 3 * NSEED + t;   // so |p-a_t|^2 >= true min
    sa[0] = ax; sa[NSEED] = ay; sa[2*NSEED] = az;
  }
}

// ---------------------------------------------------------------------------
// Kernel 2: spatial counting-sort of points into 64 cells (4x4x4, cell=0.25)
// so each wave's 64 lanes are spatially coherent -> correlated survival ->
// the ballot/queue tax is skipped on most scan iterations. Any permutation is
// correctness-neutral (per-point min, scattered back by original index).
// ---------------------------------------------------------------------------
__global__ __launch_bounds__(256) void psort_kernel(
    const float* __restrict__ pc, unsigned* __restrict__ perm)
{
  __shared__ unsigned hist[64];
  __shared__ unsigned off[64];
  int b = blockIdx.x;
  int tid = threadIdx.x;
  if (tid < 64) hist[tid] = 0u;
  __syncthreads();
  unsigned cells[16], ranks[16];
  #pragma unroll
  for (int k = 0; k < 16; ++k) {
    int i = k * 256 + tid;
    const float* pp = pc + ((size_t)b * NP + i) * 3;
    float x = pp[0], y = pp[1], z = pp[2];
    int ix = min(3, max(0, (int)(x * 4.0f)));
    int iy = min(3, max(0, (int)(y * 4.0f)));
    int iz = min(3, max(0, (int)(z * 4.0f)));
    unsigned c = (unsigned)(ix | (iy << 2) | (iz << 4));
    cells[k] = c;
    ranks[k] = atomicAdd(&hist[c], 1u);
  }
  __syncthreads();
  if (tid == 0) {
    unsigned acc = 0u;
    for (int c = 0; c < 64; ++c) { off[c] = acc; acc += hist[c]; }
  }
  __syncthreads();
  #pragma unroll
  for (int k = 0; k < 16; ++k) {
    int i = k * 256 + tid;
    perm[(size_t)b * NP + off[cells[k]] + ranks[k]] = (unsigned)i;
  }
}

// ---------------------------------------------------------------------------
// Kernel 3: seed. mind0(p) = min over a 256-chunk of seed points |p - a|^2.
// Every seed point lies on some triangle -> valid upper bound of the true min
// (safe prune threshold AND exact to fold into the output min).
// ---------------------------------------------------------------------------
__global__ __launch_bounds__(256) void seed_kernel(
    const float* __restrict__ seedA, const float* __restrict__ pc,
    float* __restrict__ partS)
{
  int bid  = blockIdx.x;
  int pblk = bid & 15;
  int vc   = (bid >> 4) & (VCH - 1);
  int b    = bid >> 7;             // VCH*16 = 128
  int p    = pblk * 256 + threadIdx.x;
  const float* pp = pc + ((size_t)b * NP + p) * 3;
  float px = pp[0], py = pp[1], pz = pp[2];
  const float* base = seedA + (size_t)b * 3 * NSEED + vc * VLEN;
  const float4* X = (const float4*)(base);
  const float4* Y = (const float4*)(base + NSEED);
  const float4* Z = (const float4*)(base + 2 * NSEED);
  float m = FLT_MAX;
  #pragma unroll 4
  for (int v = 0; v < VLEN / 4; ++v) {
    float4 vx = X[v], vy = Y[v], vz = Z[v];
    {
      float dx = px - vx.x, dy = py - vy.x, dz = pz - vz.x;
      m = fminf(m, dx*dx + dy*dy + dz*dz);
    }
    {
      float dx = px - vx.y, dy = py - vy.y, dz = pz - vz.y;
      m = fminf(m, dx*dx + dy*dy + dz*dz);
    }
    {
      float dx = px - vx.z, dy = py - vy.z, dz = pz - vz.z;
      m = fminf(m, dx*dx + dy*dy + dz*dz);
    }
    {
      float dx = px - vx.w, dy = py - vy.w, dz = pz - vz.w;
      m = fminf(m, dx*dx + dy*dy + dz*dz);
    }
  }
  partS[((size_t)b * VCH + vc) * NP + p] = m;
}

// ---------------------------------------------------------------------------
// Kernel 4: pruned main pass. Scan = slab AND centroid-sphere lower bounds
// (~15 VALU/pair, 2 x float4 record); survivors -> per-wave ballot-compacted
// LDS ring queue; full-exec batch drains evaluate 64 different (point,tri)
// pairs. Argmin is never pruned -> exact.
// ---------------------------------------------------------------------------
__global__ __launch_bounds__(256) void main_kernel(
    const float* __restrict__ triS, const float* __restrict__ triE,
    const float* __restrict__ pc, const float* __restrict__ partS,
    const unsigned* __restrict__ perm, float* __restrict__ partM)
{
  __shared__ unsigned qbuf[4][128];   // per-wave candidate ring: (tri<<6)|lane
  __shared__ unsigned wmind[4][64];   // per-wave authoritative mind (float bits)

  int bid  = blockIdx.x;
  int pblk = bid & 15;
  int s    = (bid >> 4) & (MNS - 1);
  int b    = bid >> 9;
  int tid  = threadIdx.x;
  int wave = tid >> 6, lane = tid & 63;
  int p    = (int)perm[(size_t)b * NP + pblk * 256 + tid];  // sorted -> coherent

  const float* pp = pc + ((size_t)b * NP + p) * 3;
  float px = pp[0], py = pp[1], pz = pp[2];

  float mind = FLT_MAX;
  #pragma unroll
  for (int j = 0; j < VCH; ++j)
    mind = fminf(mind, partS[((size_t)b * VCH + j) * NP + p]);
  wmind[wave][lane] = __float_as_uint(mind);   // >= 0: u32 order == f32 order
  float mth   = mind + 1e-8f;                  // slab threshold (2% in nhat)
  float smind = sqrtf(mind) * 1.005f + 1e-5f;  // sphere threshold root

  unsigned qcnt = 0u, qd = 0u;                 // wave-uniform (ballot-derived)
  const float* triEB = triE + (size_t)b * NT * TEE;
  int tg0 = s * MTCH;
  const float4* Rs = (const float4*)(triS + (size_t)(b * NT + tg0) * TSE);

#define DRAIN_BATCH(NACT)                                                     \
  {                                                                           \
    unsigned ent = qbuf[wave][(qd + (unsigned)lane) & 127u];                  \
    if ((unsigned)lane < (unsigned)(NACT)) {                                  \
      int te  = (int)(ent >> 6);                                              \
      int src = (int)(ent & 63u);                                             \
      float qx = __shfl(px, src, 64);                                         \
      float qy = __shfl(py, src, 64);                                         \
      float qz = __shfl(pz, src, 64);                                         \
      const float* rr = triEB + (size_t)te * TEE;                             \
      float4 w1 = *(const float4*)(rr + 0);                                   \
      float4 w2 = *(const float4*)(rr + 4);                                   \
      float4 w3 = *(const float4*)(rr + 8);                                   \
      float4 w4 = *(const float4*)(rr + 12);                                  \
      float4 w5 = *(const float4*)(rr + 16);                                  \
      float dd = fmaxf(tri_dist(qx, qy, qz,                                   \
                                w1.x, w1.y, w1.z,                             \
                                w1.w, w2.x, w2.y,                             \
                                w2.z, w2.w, w3.x,                             \
                                w3.y, w3.z, w3.w,                             \
                                w4.x, w4.y, w4.z,                             \
                                w4.w, w5.x, w5.y, w5.z), 0.0f);               \
      atomicMin(&wmind[wave][src], __float_as_uint(dd));                      \
    }                                                                         \
    qd += (unsigned)(NACT);                                                   \
    mind  = fminf(mind, __uint_as_float(wmind[wave][lane]));                  \
    mth   = mind + 1e-8f;                                                     \
    smind = sqrtf(mind) * 1.005f + 1e-5f;                                     \
  }

// Q0 = [nhx nhy nhz w], Q1 = [qx qy qz R]
#define SCAN_ITER(Q0, Q1, TIDX)                                               \
  {                                                                           \
    float sN  = fmaf(pz, (Q0).z, fmaf(py, (Q0).y, fmaf(px, (Q0).x, (Q0).w))); \
    float dqx = px - (Q1).x, dqy = py - (Q1).y, dqz = pz - (Q1).z;            \
    float dq2 = fmaf(dqx, dqx, fmaf(dqy, dqy, dqz * dqz));                    \
    float tt  = smind + (Q1).w;                                               \
    bool pred = (sN * sN < mth) & (dq2 < tt * tt);                            \
    unsigned long long mask = __ballot(pred);                                 \
    if (mask) {                                                               \
      if (pred) {                                                             \
        int prefix = __builtin_amdgcn_mbcnt_hi((unsigned)(mask >> 32),        \
                       __builtin_amdgcn_mbcnt_lo((unsigned)mask, 0));         \
        qbuf[wave][(qcnt + (unsigned)prefix) & 127u] =                        \
            ((unsigned)(TIDX) << 6) | (unsigned)lane;                         \
      }                                                                       \
      qcnt += (unsigned)__builtin_popcountll(mask);                           \
      if (qcnt - qd >= 64u) DRAIN_BATCH(64u);                                 \
    }                                                                         \
  }

  // group-of-2 scan with 1-group-ahead prefetch (uniform loads). Final
  // prefetch overruns into triE (contiguous in workspace), values unused.
  float4 a0 = Rs[0], a1 = Rs[1];
  float4 b0 = Rs[2], b1 = Rs[3];
  int tg = tg0;
  for (int g = 0; g < MTCH / 2; ++g) {
    const float4* Rn = Rs + 4;
    float4 c0 = Rn[0], c1 = Rn[1];
    float4 d0 = Rn[2], d1 = Rn[3];
    SCAN_ITER(a0, a1, tg + 0);
    SCAN_ITER(b0, b1, tg + 1);
    a0 = c0; a1 = c1; b0 = d0; b1 = d1;
    Rs = Rn; tg += 2;
  }

  unsigned pend = qcnt - qd;
  if (pend) DRAIN_BATCH(pend);
  mind = fminf(mind, __uint_as_float(wmind[wave][lane]));

  partM[((size_t)b * MNS + s) * NP + p] = fmaxf(mind, 0.0f);  // scatter: orig p

#undef SCAN_ITER
#undef DRAIN_BATCH
}

// ---------------------------------------------------------------------------
// Kernel 5: reduce + fused final. 64 blocks write per-block partials; last
// block (device-scope ticket) re-reads them via atomic RMW (coherent across
// XCDs) and replicates the original sequential final summation order.
// ---------------------------------------------------------------------------
__global__ __launch_bounds__(256) void reduce_kernel(
    const float* __restrict__ part, const float* __restrict__ pc,
    float* __restrict__ bl2, unsigned* __restrict__ cnt,
    float* __restrict__ out)
{
  int blk = blockIdx.x;
  int b = blk >> 4;
  int p = (blk & 15) * 256 + threadIdx.x;
  float m = FLT_MAX;
  #pragma unroll
  for (int s = 0; s < MNS; ++s)
    m = fminf(m, part[((size_t)b * MNS + s) * NP + p]);
  const float* pp = pc + ((size_t)b * NP + p) * 3;
  float x = pp[0], y = pp[1], z = pp[2];
  float msk = ((x != 0.0f) | (y != 0.0f) | (z != 0.0f)) ? 1.0f : 0.0f;
  float sdm = m * msk, sm = msk;
  for (int off = 32; off > 0; off >>= 1) {
    sdm += __shfl_down(sdm, off, 64);
    sm  += __shfl_down(sm,  off, 64);
  }
  __shared__ float s1[4], s2[4];
  __shared__ bool last;
  int wave = threadIdx.x >> 6, lanei = threadIdx.x & 63;
  if (lanei == 0) { s1[wave] = sdm; s2[wave] = sm; }
  __syncthreads();
  if (threadIdx.x == 0) {
    bl2[2 * blk]     = s1[0] + s1[1] + s1[2] + s1[3];
    bl2[2 * blk + 1] = s2[0] + s2[1] + s2[2] + s2[3];
    __threadfence();                       // publish before ticket
    unsigned t = atomicAdd(cnt, 1u);
    last = (t == 63u);
  }
  __syncthreads();
  if (last) {
    __shared__ float f1[64], f2[64];
    if (threadIdx.x < 64) {
      // atomic RMW read -> device-coherent across XCDs
      f1[threadIdx.x] = atomicAdd(&bl2[2 * threadIdx.x],     0.0f);
      f2[threadIdx.x] = atomicAdd(&bl2[2 * threadIdx.x + 1], 0.0f);
    }
    __syncthreads();
    if (threadIdx.x == 0) {
      float acc = 0.0f;
      for (int bb = 0; bb < NB; ++bb) {
        float tsd = 0.0f, tsm = 0.0f;
        for (int k = 0; k < 16; ++k) {
          tsd += f1[bb * 16 + k];
          tsm += f2[bb * 16 + k];
        }
        acc += tsd / fmaxf(tsm, 1.0f);
      }
      out[0] = 0.25f * acc;
    }
  }
}

extern "C" void kernel_launch(void* const* d_in, const int* in_sizes, int n_in,
                              void* d_out, int out_size, void* d_ws, size_t ws_size,
                              hipStream_t stream) {
  const float* verts = (const float*)d_in[0];   // (4,3,16,16,16) f32
  const float* pc    = (const float*)d_in[1];   // (4,4096,3) f32
  const int*   faces = (const int*)d_in[2];     // (8192,3) i32
  float* out = (float*)d_out;

  float* triS  = (float*)d_ws;                        // NB*NT*8   =  262144 floats
  float* triE  = triS  + (size_t)NB * NT * TSE;       // NB*NT*20  =  655360
  float* seedA = triE  + (size_t)NB * NT * TEE;       // NB*3*2048 =   24576
  float* partS = seedA + (size_t)NB * 3 * NSEED;      // NB*VCH*NP =  131072
  float* partM = partS + (size_t)NB * VCH * NP;       // NB*MNS*NP =  524288
  float* bl2   = partM + (size_t)NB * MNS * NP;       // 128
  unsigned* cnt  = (unsigned*)(bl2 + 128);            // 1
  unsigned* perm = (unsigned*)(bl2 + 132);            // NB*NP = 16384 u32

  prep_kernel<<<(NB * NT) / 256, 256, 0, stream>>>(verts, faces, triS, triE, seedA, cnt);
  psort_kernel<<<NB, 256, 0, stream>>>(pc, perm);
  seed_kernel<<<NB * VCH * 16, 256, 0, stream>>>(seedA, pc, partS);
  main_kernel<<<NB * MNS * 16, 256, 0, stream>>>(triS, triE, pc, partS, perm, partM);
  reduce_kernel<<<NB * 16, 256, 0, stream>>>(partM, pc, bl2, cnt, out);
}